// Round 1
// baseline (49.928 us; speedup 1.0000x reference)
//
#include <hip/hip_runtime.h>
#include <hip/hip_bf16.h>
#include <math.h>

#define H 2048
#define L 350

__device__ __forceinline__ float wave_reduce_sum(float v) {
    #pragma unroll
    for (int off = 32; off > 0; off >>= 1) v += __shfl_down(v, off, 64);
    return v;  // lane 0 holds the 64-lane sum
}

__device__ __forceinline__ float dot4(float4 a, float4 b, float acc) {
    acc = fmaf(a.x, b.x, acc);
    acc = fmaf(a.y, b.y, acc);
    acc = fmaf(a.z, b.z, acc);
    acc = fmaf(a.w, b.w, acc);
    return acc;
}

// logits[row] = dot(x, W[row, 0:2048]) + dot(h, W[row, 2048:4096]) + b[row]
__global__ __launch_bounds__(256) void attn_logits_kernel(
    const float* __restrict__ x, const float* __restrict__ h,
    const float* __restrict__ W, const float* __restrict__ b,
    float* __restrict__ logits)
{
    __shared__ float red[4];
    const int row = blockIdx.x;
    const float4* Wr = reinterpret_cast<const float4*>(W + (size_t)row * (2 * H));
    const float4* x4 = reinterpret_cast<const float4*>(x);
    const float4* h4 = reinterpret_cast<const float4*>(h);
    float acc = 0.f;
    for (int i = threadIdx.x; i < H / 4; i += 256) {        // 512 float4 per half
        acc = dot4(Wr[i], x4[i], acc);
        acc = dot4(Wr[H / 4 + i], h4[i], acc);
    }
    acc = wave_reduce_sum(acc);
    const int wid = threadIdx.x >> 6, lane = threadIdx.x & 63;
    if (lane == 0) red[wid] = acc;
    __syncthreads();
    if (threadIdx.x == 0)
        logits[row] = red[0] + red[1] + red[2] + red[3] + b[row];
}

// softmax over 350 logits -> attn (single block, 512 threads)
__global__ __launch_bounds__(512) void softmax_kernel(
    const float* __restrict__ logits, float* __restrict__ attn)
{
    __shared__ float red[512];
    const int t = threadIdx.x;
    float v = (t < L) ? logits[t] : -INFINITY;
    red[t] = v;
    __syncthreads();
    #pragma unroll
    for (int s = 256; s > 0; s >>= 1) {
        if (t < s) red[t] = fmaxf(red[t], red[t + s]);
        __syncthreads();
    }
    const float m = red[0];
    __syncthreads();
    float e = (t < L) ? expf(v - m) : 0.f;
    red[t] = e;
    __syncthreads();
    #pragma unroll
    for (int s = 256; s > 0; s >>= 1) {
        if (t < s) red[t] += red[t + s];
        __syncthreads();
    }
    const float inv = 1.f / red[0];
    if (t < L) attn[t] = e * inv;
}

// ctx[i] = sum_j attn[j] * enc[j, i]
__global__ __launch_bounds__(256) void context_kernel(
    const float* __restrict__ attn, const float* __restrict__ enc,
    float* __restrict__ ctx)
{
    __shared__ float w[L];
    for (int j = threadIdx.x; j < L; j += 256) w[j] = attn[j];
    __syncthreads();
    const int i = blockIdx.x * 256 + threadIdx.x;
    float acc = 0.f;
    for (int j = 0; j < L; ++j)
        acc = fmaf(w[j], enc[(size_t)j * H + i], acc);
    ctx[i] = acc;
}

// g[row] = relu(dot(x, W[row,0:2048]) + dot(ctx, W[row,2048:4096]) + b[row]);
// one wave per row, 4 waves/block
__global__ __launch_bounds__(256) void combine_kernel(
    const float* __restrict__ x, const float* __restrict__ ctx,
    const float* __restrict__ W, const float* __restrict__ b,
    float* __restrict__ g)
{
    const int wave = (blockIdx.x * 256 + threadIdx.x) >> 6;
    const int lane = threadIdx.x & 63;
    const float4* Wr = reinterpret_cast<const float4*>(W + (size_t)wave * (2 * H));
    const float4* x4 = reinterpret_cast<const float4*>(x);
    const float4* c4 = reinterpret_cast<const float4*>(ctx);
    float acc = 0.f;
    #pragma unroll
    for (int i = lane; i < H / 4; i += 64) {
        acc = dot4(Wr[i], x4[i], acc);
        acc = dot4(Wr[H / 4 + i], c4[i], acc);
    }
    acc = wave_reduce_sum(acc);
    if (lane == 0) g[wave] = fmaxf(acc + b[wave], 0.f);
}

// rows 0..6143: gi[row] = dot(g, w_ih[row]) + b_ih[row]
// rows 6144..12287: gh[row-6144] = dot(h, w_hh[row-6144]) + b_hh[row-6144]
__global__ __launch_bounds__(256) void gru_gemv_kernel(
    const float* __restrict__ g, const float* __restrict__ h,
    const float* __restrict__ w_ih, const float* __restrict__ w_hh,
    const float* __restrict__ b_ih, const float* __restrict__ b_hh,
    float* __restrict__ gi, float* __restrict__ gh)
{
    const int wave = (blockIdx.x * 256 + threadIdx.x) >> 6;
    const int lane = threadIdx.x & 63;
    const float* vec; const float* W; const float* b; float* out; int row;
    if (wave < 3 * H) { row = wave;          vec = g; W = w_ih; b = b_ih; out = gi; }
    else              { row = wave - 3 * H;  vec = h; W = w_hh; b = b_hh; out = gh; }
    const float4* Wr = reinterpret_cast<const float4*>(W + (size_t)row * H);
    const float4* v4 = reinterpret_cast<const float4*>(vec);
    float acc = 0.f;
    #pragma unroll
    for (int i = lane; i < H / 4; i += 64) acc = dot4(Wr[i], v4[i], acc);
    acc = wave_reduce_sum(acc);
    if (lane == 0) out[row] = acc + b[row];
}

// GRU gates + write outputs (h_new twice)
__global__ __launch_bounds__(256) void gates_kernel(
    const float* __restrict__ gi, const float* __restrict__ gh,
    const float* __restrict__ h, float* __restrict__ out)
{
    const int i = blockIdx.x * 256 + threadIdx.x;
    const float ir = gi[i],     hr = gh[i];
    const float iz = gi[H + i], hz = gh[H + i];
    const float in_ = gi[2 * H + i], hn = gh[2 * H + i];
    const float r = 1.f / (1.f + expf(-(ir + hr)));
    const float z = 1.f / (1.f + expf(-(iz + hz)));
    const float n = tanhf(in_ + r * hn);
    const float hnew = (1.f - z) * n + z * h[i];
    out[i] = hnew;          // output
    out[H + i] = hnew;      // h_new
}

extern "C" void kernel_launch(void* const* d_in, const int* in_sizes, int n_in,
                              void* d_out, int out_size, void* d_ws, size_t ws_size,
                              hipStream_t stream)
{
    const float* input  = (const float*)d_in[0];
    const float* hidden = (const float*)d_in[1];
    const float* enc    = (const float*)d_in[2];
    const float* attn_W = (const float*)d_in[3];
    const float* attn_b = (const float*)d_in[4];
    const float* comb_W = (const float*)d_in[5];
    const float* comb_b = (const float*)d_in[6];
    const float* w_ih   = (const float*)d_in[7];
    const float* w_hh   = (const float*)d_in[8];
    const float* b_ih   = (const float*)d_in[9];
    const float* b_hh   = (const float*)d_in[10];
    float* out = (float*)d_out;
    float* ws  = (float*)d_ws;

    float* logits = ws;            // 350
    float* ctx    = ws + 512;      // 2048
    float* g      = ws + 2560;     // 2048
    float* gi     = ws + 4608;     // 6144
    float* gh     = ws + 10752;    // 6144
    float* attn   = out + 2 * H;   // 350, also an output

    attn_logits_kernel<<<L, 256, 0, stream>>>(input, hidden, attn_W, attn_b, logits);
    softmax_kernel<<<1, 512, 0, stream>>>(logits, attn);
    context_kernel<<<H / 256, 256, 0, stream>>>(attn, enc, ctx);
    combine_kernel<<<H / 4, 256, 0, stream>>>(input, ctx, comb_W, comb_b, g);
    gru_gemv_kernel<<<(6 * H) / 4, 256, 0, stream>>>(g, hidden, w_ih, w_hh, b_ih, b_hh, gi, gh);
    gates_kernel<<<H / 256, 256, 0, stream>>>(gi, gh, hidden, out);
}